// Round 1
// baseline (134.244 us; speedup 1.0000x reference)
//
#include <hip/hip_runtime.h>
#include <hip/hip_bf16.h>

#define BB   8192
#define SS   64
#define NIN  128
#define NH   64

typedef __attribute__((ext_vector_type(8))) short  short8;
typedef __attribute__((ext_vector_type(4))) float  f32x4;

__device__ __forceinline__ unsigned short f2b(float f) {
    unsigned int u = __float_as_uint(f);
    u += 0x7FFF + ((u >> 16) & 1);          // round-to-nearest-even
    return (unsigned short)(u >> 16);
}

__device__ __forceinline__ short8 cvt8(float4 x0, float4 x1) {
    short8 r;
    r[0] = (short)f2b(x0.x); r[1] = (short)f2b(x0.y);
    r[2] = (short)f2b(x0.z); r[3] = (short)f2b(x0.w);
    r[4] = (short)f2b(x1.x); r[5] = (short)f2b(x1.y);
    r[6] = (short)f2b(x1.z); r[7] = (short)f2b(x1.w);
    return r;
}

// ---- kernel 0: W_fc f32 -> bf16 (natural [h][i] layout) into workspace ----
__global__ void conv_wfc(const float* __restrict__ wf, unsigned short* __restrict__ wb) {
    int i = blockIdx.x * blockDim.x + threadIdx.x;
    if (i < NH * NIN) wb[i] = f2b(wf[i]);
}

// ---- kernel 1: per-batch fused GCN: GEMM1 -> GEMM2 -> PReLU -> mean/row ----
__global__ __launch_bounds__(256) void fused_gcn(
    const float* __restrict__ seq1, const float* __restrict__ adj,
    const unsigned short* __restrict__ wfc, const float* __restrict__ b_gcn,
    const float* __restrict__ prelu_a, float* __restrict__ out_hmv,
    float* __restrict__ out_c)
{
    __shared__ unsigned short ftsT[NH][72];   // [h][s], stride 72 bf16 = 144 B (16-aligned, bank-clean)
    __shared__ float c_part[4][NH];

    const int b   = blockIdx.x;
    const int tid = threadIdx.x;
    const int w   = tid >> 6;   // wave 0..3 -> s-strip
    const int l   = tid & 63;
    const int m   = l & 15;
    const int g   = l >> 4;

    const float* seqb = seq1 + (size_t)b * (SS * NIN);
    const float* adjb = adj  + (size_t)b * (SS * SS);

    const int srow = 16 * w + m;             // M row for A fragments

    // ---------- GEMM1: fts[s][h] = sum_i seq1[s][i] * W_fc[h][i] ----------
    f32x4 acc1[4];
    #pragma unroll
    for (int hj = 0; hj < 4; ++hj)
        for (int r = 0; r < 4; ++r) acc1[hj][r] = 0.f;

    #pragma unroll
    for (int kk = 0; kk < 4; ++kk) {
        const int k0 = 32 * kk + 8 * g;
        const float4* ap = reinterpret_cast<const float4*>(seqb + srow * NIN + k0);
        float4 x0 = ap[0], x1 = ap[1];
        short8 af = cvt8(x0, x1);
        #pragma unroll
        for (int hj = 0; hj < 4; ++hj) {
            short8 bf = *reinterpret_cast<const short8*>(wfc + (16 * hj + m) * NIN + k0);
            acc1[hj] = __builtin_amdgcn_mfma_f32_16x16x32_bf16(af, bf, acc1[hj], 0, 0, 0);
        }
    }

    // write fts^T (bf16) to LDS: lane holds fts[s=16w+4g+r][h=16hj+m]
    {
        const int s0 = 16 * w + 4 * g;
        #pragma unroll
        for (int hj = 0; hj < 4; ++hj) {
            const int h = 16 * hj + m;
            uint2 pk;
            pk.x = (unsigned)f2b(acc1[hj][0]) | ((unsigned)f2b(acc1[hj][1]) << 16);
            pk.y = (unsigned)f2b(acc1[hj][2]) | ((unsigned)f2b(acc1[hj][3]) << 16);
            *reinterpret_cast<uint2*>(&ftsT[h][s0]) = pk;
        }
    }
    __syncthreads();

    // ---------- GEMM2: out[s][h] = sum_t adj[s][t] * fts[t][h] ----------
    f32x4 acc2[4];
    #pragma unroll
    for (int hj = 0; hj < 4; ++hj)
        for (int r = 0; r < 4; ++r) acc2[hj][r] = 0.f;

    #pragma unroll
    for (int kk = 0; kk < 2; ++kk) {
        const int k0 = 32 * kk + 8 * g;
        const float4* ap = reinterpret_cast<const float4*>(adjb + srow * SS + k0);
        float4 x0 = ap[0], x1 = ap[1];
        short8 af = cvt8(x0, x1);
        #pragma unroll
        for (int hj = 0; hj < 4; ++hj) {
            short8 bf = *reinterpret_cast<const short8*>(&ftsT[16 * hj + m][k0]);
            acc2[hj] = __builtin_amdgcn_mfma_f32_16x16x32_bf16(af, bf, acc2[hj], 0, 0, 0);
        }
    }

    // ---------- bias + PReLU + column mean (s<63) + row s==63 ----------
    const float pa = *prelu_a;
    const int s_base = 16 * w + 4 * g;
    #pragma unroll
    for (int hj = 0; hj < 4; ++hj) {
        const int h = 16 * hj + m;
        const float bg = b_gcn[h];
        float part = 0.f;
        #pragma unroll
        for (int r = 0; r < 4; ++r) {
            float v = acc2[hj][r] + bg;
            v = (v >= 0.f) ? v : pa * v;
            const int s = s_base + r;
            if (s < SS - 1) part += v;
            else            out_hmv[(size_t)b * NH + h] = v;   // s == 63
        }
        // reduce over the 4 k-groups (lanes xor 16, 32) -> per-h strip sum
        part += __shfl_xor(part, 16);
        part += __shfl_xor(part, 32);
        if (g == 0) c_part[w][h] = part;
    }
    __syncthreads();
    if (tid < NH) {
        float tot = c_part[0][tid] + c_part[1][tid] + c_part[2][tid] + c_part[3][tid];
        out_c[(size_t)b * NH + tid] = tot * (1.0f / 63.0f);
    }
}

// ---- kernel 2: bilinear logits, one wave per batch ----
__global__ __launch_bounds__(256) void bilinear_k(
    const float* __restrict__ hmv, const float* __restrict__ c,
    const float* __restrict__ W_bil, const float* __restrict__ b_bil,
    float* __restrict__ logits)
{
    const int gw = (int)((blockIdx.x * blockDim.x + threadIdx.x) >> 6); // batch
    const int l  = threadIdx.x & 63;
    if (gw >= BB) return;
    const int b = gw;

    float h_l = hmv[(size_t)b * NH + l];
    // v_j = sum_i h[i] * W[i][j]  (lane j = l)
    float v = 0.f;
    #pragma unroll 8
    for (int i = 0; i < NH; ++i) {
        float hi = __shfl(h_l, i);
        v = fmaf(hi, W_bil[i * NH + l], v);
    }
    const float cj = c[(size_t)b * NH + l];
    const int bprev = (b == 0) ? (BB - 2) : (b - 1);
    const float cpj = c[(size_t)bprev * NH + l];

    float t0 = v * cj, t1 = v * cpj;
    #pragma unroll
    for (int off = 32; off; off >>= 1) {
        t0 += __shfl_xor(t0, off);
        t1 += __shfl_xor(t1, off);
    }
    if (l == 0) {
        const float bb = b_bil[0];
        logits[b]      = t0 + bb;
        logits[BB + b] = t1 + bb;
    }
}

extern "C" void kernel_launch(void* const* d_in, const int* in_sizes, int n_in,
                              void* d_out, int out_size, void* d_ws, size_t ws_size,
                              hipStream_t stream) {
    const float* seq1    = (const float*)d_in[0];
    const float* adj     = (const float*)d_in[1];
    const float* W_fc    = (const float*)d_in[2];
    const float* b_gcn   = (const float*)d_in[3];
    const float* prelu_a = (const float*)d_in[4];
    const float* W_bil   = (const float*)d_in[5];
    const float* b_bil   = (const float*)d_in[6];

    float* out    = (float*)d_out;
    float* logits = out;                       // 2*BB
    float* hmv    = out + 2 * BB;              // BB*NH
    float* cc     = hmv + (size_t)BB * NH;     // BB*NH

    unsigned short* wfc_bf = (unsigned short*)d_ws;   // NH*NIN bf16 = 16 KiB

    conv_wfc<<<(NH * NIN + 255) / 256, 256, 0, stream>>>(W_fc, wfc_bf);
    fused_gcn<<<BB, 256, 0, stream>>>(seq1, adj, wfc_bf, b_gcn, prelu_a, hmv, cc);
    bilinear_k<<<(BB * 64 + 255) / 256, 256, 0, stream>>>(hmv, cc, W_bil, b_bil, logits);
}

// Round 2
// 127.542 us; speedup vs baseline: 1.0525x; 1.0525x over previous
//
#include <hip/hip_runtime.h>
#include <hip/hip_bf16.h>

#define BB   8192
#define SS   64
#define NIN  128
#define NH   64

typedef __attribute__((ext_vector_type(8))) short  short8;
typedef __attribute__((ext_vector_type(4))) float  f32x4;

__device__ __forceinline__ unsigned short f2b(float f) {
    unsigned int u = __float_as_uint(f);
    u += 0x7FFF + ((u >> 16) & 1);          // round-to-nearest-even
    return (unsigned short)(u >> 16);
}

__device__ __forceinline__ short8 cvt8(float4 x0, float4 x1) {
    short8 r;
    r[0] = (short)f2b(x0.x); r[1] = (short)f2b(x0.y);
    r[2] = (short)f2b(x0.z); r[3] = (short)f2b(x0.w);
    r[4] = (short)f2b(x1.x); r[5] = (short)f2b(x1.y);
    r[6] = (short)f2b(x1.z); r[7] = (short)f2b(x1.w);
    return r;
}

// ---- kernel 0: W_fc f32 -> bf16 (natural [h][i] layout) into workspace ----
__global__ void conv_wfc(const float* __restrict__ wf, unsigned short* __restrict__ wb) {
    int i = blockIdx.x * blockDim.x + threadIdx.x;
    if (i < NH * NIN) wb[i] = f2b(wf[i]);
}

// ---- kernel 1: per-batch fused GCN: GEMM1 -> GEMM2 -> PReLU -> mean/row ----
// All global loads for the batch are issued UP FRONT (seq1 8x16B + adj 4x16B
// per lane) so the block never sits with an empty memory queue; adj bf16
// conversion happens before the barrier to overlap the LDS transpose.
__global__ __launch_bounds__(256) void fused_gcn(
    const float* __restrict__ seq1, const float* __restrict__ adj,
    const unsigned short* __restrict__ wfc, const float* __restrict__ b_gcn,
    const float* __restrict__ prelu_a, float* __restrict__ out_hmv,
    float* __restrict__ out_c)
{
    __shared__ unsigned short ftsT[NH][72];   // [h][s], stride 72 bf16 = 144 B
    __shared__ float c_part[4][NH];

    const int b   = blockIdx.x;
    const int tid = threadIdx.x;
    const int w   = tid >> 6;   // wave 0..3 -> s-strip
    const int l   = tid & 63;
    const int m   = l & 15;
    const int g   = l >> 4;

    const float* seqb = seq1 + (size_t)b * (SS * NIN);
    const float* adjb = adj  + (size_t)b * (SS * SS);

    const int srow = 16 * w + m;             // M row for A fragments

    // ---------- issue ALL global loads up front ----------
    const float4* sp = reinterpret_cast<const float4*>(seqb + srow * NIN);
    const float4* ap = reinterpret_cast<const float4*>(adjb + srow * SS);
    float4 sA0 = sp[ 0 + 2 * g], sA1 = sp[ 1 + 2 * g];
    float4 sB0 = sp[ 8 + 2 * g], sB1 = sp[ 9 + 2 * g];
    float4 sC0 = sp[16 + 2 * g], sC1 = sp[17 + 2 * g];
    float4 sD0 = sp[24 + 2 * g], sD1 = sp[25 + 2 * g];
    float4 aA0 = ap[ 0 + 2 * g], aA1 = ap[ 1 + 2 * g];
    float4 aB0 = ap[ 8 + 2 * g], aB1 = ap[ 9 + 2 * g];

    // ---------- GEMM1: fts[s][h] = sum_i seq1[s][i] * W_fc[h][i] ----------
    f32x4 acc1[4];
    #pragma unroll
    for (int hj = 0; hj < 4; ++hj)
        for (int r = 0; r < 4; ++r) acc1[hj][r] = 0.f;

    short8 af0 = cvt8(sA0, sA1);
    short8 af1 = cvt8(sB0, sB1);
    short8 af2 = cvt8(sC0, sC1);
    short8 af3 = cvt8(sD0, sD1);

    #pragma unroll
    for (int hj = 0; hj < 4; ++hj) {
        const unsigned short* wr = wfc + (16 * hj + m) * NIN + 8 * g;
        short8 b0 = *reinterpret_cast<const short8*>(wr);
        short8 b1 = *reinterpret_cast<const short8*>(wr + 32);
        short8 b2 = *reinterpret_cast<const short8*>(wr + 64);
        short8 b3 = *reinterpret_cast<const short8*>(wr + 96);
        acc1[hj] = __builtin_amdgcn_mfma_f32_16x16x32_bf16(af0, b0, acc1[hj], 0, 0, 0);
        acc1[hj] = __builtin_amdgcn_mfma_f32_16x16x32_bf16(af1, b1, acc1[hj], 0, 0, 0);
        acc1[hj] = __builtin_amdgcn_mfma_f32_16x16x32_bf16(af2, b2, acc1[hj], 0, 0, 0);
        acc1[hj] = __builtin_amdgcn_mfma_f32_16x16x32_bf16(af3, b3, acc1[hj], 0, 0, 0);
    }

    // convert adj fragments now (overlaps the LDS transpose below)
    short8 adjf0 = cvt8(aA0, aA1);
    short8 adjf1 = cvt8(aB0, aB1);

    // write fts^T (bf16) to LDS: lane holds fts[s=16w+4g+r][h=16hj+m]
    {
        const int s0 = 16 * w + 4 * g;
        #pragma unroll
        for (int hj = 0; hj < 4; ++hj) {
            const int h = 16 * hj + m;
            uint2 pk;
            pk.x = (unsigned)f2b(acc1[hj][0]) | ((unsigned)f2b(acc1[hj][1]) << 16);
            pk.y = (unsigned)f2b(acc1[hj][2]) | ((unsigned)f2b(acc1[hj][3]) << 16);
            *reinterpret_cast<uint2*>(&ftsT[h][s0]) = pk;
        }
    }
    __syncthreads();

    // ---------- GEMM2: out[s][h] = sum_t adj[s][t] * fts[t][h] ----------
    f32x4 acc2[4];
    #pragma unroll
    for (int hj = 0; hj < 4; ++hj)
        for (int r = 0; r < 4; ++r) acc2[hj][r] = 0.f;

    #pragma unroll
    for (int hj = 0; hj < 4; ++hj) {
        const unsigned short* fr = &ftsT[16 * hj + m][8 * g];
        short8 b0 = *reinterpret_cast<const short8*>(fr);
        short8 b1 = *reinterpret_cast<const short8*>(fr + 32);
        acc2[hj] = __builtin_amdgcn_mfma_f32_16x16x32_bf16(adjf0, b0, acc2[hj], 0, 0, 0);
        acc2[hj] = __builtin_amdgcn_mfma_f32_16x16x32_bf16(adjf1, b1, acc2[hj], 0, 0, 0);
    }

    // ---------- bias + PReLU + column mean (s<63) + row s==63 ----------
    const float pa = *prelu_a;
    const int s_base = 16 * w + 4 * g;
    #pragma unroll
    for (int hj = 0; hj < 4; ++hj) {
        const int h = 16 * hj + m;
        const float bg = b_gcn[h];
        float part = 0.f;
        #pragma unroll
        for (int r = 0; r < 4; ++r) {
            float v = acc2[hj][r] + bg;
            v = (v >= 0.f) ? v : pa * v;
            const int s = s_base + r;
            if (s < SS - 1) part += v;
            else            out_hmv[(size_t)b * NH + h] = v;   // s == 63
        }
        // reduce over the 4 k-groups (lanes xor 16, 32) -> per-h strip sum
        part += __shfl_xor(part, 16);
        part += __shfl_xor(part, 32);
        if (g == 0) c_part[w][h] = part;
    }
    __syncthreads();
    if (tid < NH) {
        float tot = c_part[0][tid] + c_part[1][tid] + c_part[2][tid] + c_part[3][tid];
        out_c[(size_t)b * NH + tid] = tot * (1.0f / 63.0f);
    }
}

// ---- kernel 2: bilinear logits, one wave per batch ----
__global__ __launch_bounds__(256) void bilinear_k(
    const float* __restrict__ hmv, const float* __restrict__ c,
    const float* __restrict__ W_bil, const float* __restrict__ b_bil,
    float* __restrict__ logits)
{
    const int gw = (int)((blockIdx.x * blockDim.x + threadIdx.x) >> 6); // batch
    const int l  = threadIdx.x & 63;
    if (gw >= BB) return;
    const int b = gw;

    float h_l = hmv[(size_t)b * NH + l];
    // v_j = sum_i h[i] * W[i][j]  (lane j = l); two partials shorten the chain
    float v0 = 0.f, v1 = 0.f;
    #pragma unroll 8
    for (int i = 0; i < NH; i += 2) {
        float hi0 = __shfl(h_l, i);
        float hi1 = __shfl(h_l, i + 1);
        v0 = fmaf(hi0, W_bil[i * NH + l], v0);
        v1 = fmaf(hi1, W_bil[(i + 1) * NH + l], v1);
    }
    const float v = v0 + v1;
    const float cj = c[(size_t)b * NH + l];
    const int bprev = (b == 0) ? (BB - 2) : (b - 1);
    const float cpj = c[(size_t)bprev * NH + l];

    float t0 = v * cj, t1 = v * cpj;
    #pragma unroll
    for (int off = 32; off; off >>= 1) {
        t0 += __shfl_xor(t0, off);
        t1 += __shfl_xor(t1, off);
    }
    if (l == 0) {
        const float bb = b_bil[0];
        logits[b]      = t0 + bb;
        logits[BB + b] = t1 + bb;
    }
}

extern "C" void kernel_launch(void* const* d_in, const int* in_sizes, int n_in,
                              void* d_out, int out_size, void* d_ws, size_t ws_size,
                              hipStream_t stream) {
    const float* seq1    = (const float*)d_in[0];
    const float* adj     = (const float*)d_in[1];
    const float* W_fc    = (const float*)d_in[2];
    const float* b_gcn   = (const float*)d_in[3];
    const float* prelu_a = (const float*)d_in[4];
    const float* W_bil   = (const float*)d_in[5];
    const float* b_bil   = (const float*)d_in[6];

    float* out    = (float*)d_out;
    float* logits = out;                       // 2*BB
    float* hmv    = out + 2 * BB;              // BB*NH
    float* cc     = hmv + (size_t)BB * NH;     // BB*NH

    unsigned short* wfc_bf = (unsigned short*)d_ws;   // NH*NIN bf16 = 16 KiB

    conv_wfc<<<(NH * NIN + 255) / 256, 256, 0, stream>>>(W_fc, wfc_bf);
    fused_gcn<<<BB, 256, 0, stream>>>(seq1, adj, wfc_bf, b_gcn, prelu_a, hmv, cc);
    bilinear_k<<<(BB * 64 + 255) / 256, 256, 0, stream>>>(hmv, cc, W_bil, b_bil, logits);
}

// Round 3
// 90.471 us; speedup vs baseline: 1.4838x; 1.4098x over previous
//
#include <hip/hip_runtime.h>
#include <hip/hip_bf16.h>

#define BB   8192
#define SS   64
#define NIN  128
#define NH   64
#define NB   8            // batches per block (fused kernel)
#define GRID (BB / NB)    // 1024 = 4 blocks/CU exactly

typedef __attribute__((ext_vector_type(8))) short  short8;
typedef __attribute__((ext_vector_type(4))) float  f32x4;

__device__ __forceinline__ unsigned short f2b(float f) {
    unsigned int u = __float_as_uint(f);
    u += 0x7FFF + ((u >> 16) & 1);          // RNE
    return (unsigned short)(u >> 16);
}

__device__ __forceinline__ short8 cvt8(float4 x0, float4 x1) {
    short8 r;
    r[0] = (short)f2b(x0.x); r[1] = (short)f2b(x0.y);
    r[2] = (short)f2b(x0.z); r[3] = (short)f2b(x0.w);
    r[4] = (short)f2b(x1.x); r[5] = (short)f2b(x1.y);
    r[6] = (short)f2b(x1.z); r[7] = (short)f2b(x1.w);
    return r;
}

// ---- kernel 0: W_fc and W_bil -> bf16, re-shuffled into MFMA fragment order.
// W_fc  frag: wsA[((hj*4+kk)*64 + l)*8 + e] = W_fc[16hj+m][32kk+8g+e], l=g*16+m
// W_bil frag: wsB[((kk*4+nt)*64 + l)*8 + e] = W_bil[32kk+8g+e][16nt+m]  (B-operand: k=i, n=j)
__global__ void conv_w(const float* __restrict__ wf, const float* __restrict__ wbil,
                       unsigned short* __restrict__ wsA, unsigned short* __restrict__ wsB) {
    int idx = blockIdx.x * blockDim.x + threadIdx.x;
    if (idx < NH * NIN) {
        int h = idx >> 7, i = idx & 127;
        int hj = h >> 4, m = h & 15, kk = i >> 5, g = (i >> 3) & 3, e = i & 7;
        wsA[(((hj * 4 + kk) * 64) + g * 16 + m) * 8 + e] = f2b(wf[idx]);
    } else if (idx < NH * NIN + NH * NH) {
        int q = idx - NH * NIN;
        int i = q >> 6, j = q & 63;
        int kk = i >> 5, g = (i >> 3) & 3, e = i & 7, nt = j >> 4, m = j & 15;
        wsB[(((kk * 4 + nt) * 64) + g * 16 + m) * 8 + e] = f2b(wbil[q]);
    }
}

// ---- kernel 1: persistent pipelined fused GCN ----
__global__ __launch_bounds__(256, 4) void fused_gcn(
    const float* __restrict__ seq1, const float* __restrict__ adj,
    const unsigned short* __restrict__ wsA, const float* __restrict__ b_gcn,
    const float* __restrict__ prelu_a, float* __restrict__ out_hmv,
    float* __restrict__ out_c)
{
    __shared__ short8 Wlds[1024];             // 16 KiB, fragment-ordered W_fc
    __shared__ unsigned short ftsT[NH][72];   // [h][s], stride 144 B
    __shared__ float c_part[4][NH];

    const int tid = threadIdx.x;
    const int w   = tid >> 6;
    const int l   = tid & 63;
    const int m   = l & 15;
    const int g   = l >> 4;
    const int bbase = blockIdx.x * NB;
    const int srow  = 16 * w + m;
    const int s0i   = 16 * w + 4 * g;

    // stage fragment-ordered W_fc into LDS (4 x 16B per thread, contiguous)
    {
        const uint4* src = reinterpret_cast<const uint4*>(wsA);
        uint4* dst = reinterpret_cast<uint4*>(Wlds);
        #pragma unroll
        for (int q = 0; q < 4; ++q) dst[tid + 256 * q] = src[tid + 256 * q];
    }

    const float pa = *prelu_a;
    float bg[4];
    #pragma unroll
    for (int hj = 0; hj < 4; ++hj) bg[hj] = b_gcn[16 * hj + m];

    // prefetch seq batch 0
    float4 s0, s1, s2, s3, s4, s5, s6, s7;
    {
        const float4* sp = reinterpret_cast<const float4*>(seq1 + (size_t)bbase * (SS * NIN) + srow * NIN);
        s0 = sp[0 + 2 * g];  s1 = sp[1 + 2 * g];
        s2 = sp[8 + 2 * g];  s3 = sp[9 + 2 * g];
        s4 = sp[16 + 2 * g]; s5 = sp[17 + 2 * g];
        s6 = sp[24 + 2 * g]; s7 = sp[25 + 2 * g];
    }
    __syncthreads();   // W staged (one-time full drain, amortized over NB batches)

    #pragma unroll 1
    for (int j = 0; j < NB; ++j) {
        const int b = bbase + j;

        // 1. issue adj(j) loads (oldest vmem this iter)
        const float4* ap = reinterpret_cast<const float4*>(adj + (size_t)b * (SS * SS) + srow * SS);
        float4 a0 = ap[0 + 2 * g], a1 = ap[1 + 2 * g];
        float4 a2 = ap[8 + 2 * g], a3 = ap[9 + 2 * g];

        // 2. cvt seq(j) (regs die here -> reusable)
        short8 af[4];
        af[0] = cvt8(s0, s1); af[1] = cvt8(s2, s3);
        af[2] = cvt8(s4, s5); af[3] = cvt8(s6, s7);

        // 3. prefetch seq(j+1) — stays in flight across BOTH raw barriers
        if (j + 1 < NB) {
            const float4* sp = reinterpret_cast<const float4*>(seq1 + (size_t)(b + 1) * (SS * NIN) + srow * NIN);
            s0 = sp[0 + 2 * g];  s1 = sp[1 + 2 * g];
            s2 = sp[8 + 2 * g];  s3 = sp[9 + 2 * g];
            s4 = sp[16 + 2 * g]; s5 = sp[17 + 2 * g];
            s6 = sp[24 + 2 * g]; s7 = sp[25 + 2 * g];
        }

        // 4. GEMM1: fts[s][h] = sum_i seq[s][i] * W_fc[h][i]  (W frags from LDS, contiguous 1KB reads)
        f32x4 acc1[4];
        #pragma unroll
        for (int hj = 0; hj < 4; ++hj)
            for (int r = 0; r < 4; ++r) acc1[hj][r] = 0.f;
        #pragma unroll
        for (int hj = 0; hj < 4; ++hj) {
            #pragma unroll
            for (int kk = 0; kk < 4; ++kk) {
                short8 bf = Wlds[(hj * 4 + kk) * 64 + l];
                acc1[hj] = __builtin_amdgcn_mfma_f32_16x16x32_bf16(af[kk], bf, acc1[hj], 0, 0, 0);
            }
        }

        // 5. pack + transpose-write fts^T to LDS
        #pragma unroll
        for (int hj = 0; hj < 4; ++hj) {
            uint2 pk;
            pk.x = (unsigned)f2b(acc1[hj][0]) | ((unsigned)f2b(acc1[hj][1]) << 16);
            pk.y = (unsigned)f2b(acc1[hj][2]) | ((unsigned)f2b(acc1[hj][3]) << 16);
            *reinterpret_cast<uint2*>(&ftsT[16 * hj + m][s0i]) = pk;
        }

        // 6. cvt adj(j)  (waits adj loads; seq(j+1) counted past, stays outstanding)
        short8 adf0 = cvt8(a0, a1);
        short8 adf1 = cvt8(a2, a3);

        // 7. raw barrier (no vmcnt drain!)
        asm volatile("s_waitcnt lgkmcnt(0)" ::: "memory");
        __builtin_amdgcn_s_barrier();
        asm volatile("" ::: "memory");

        // 8. GEMM2: out[s][h] = sum_t adj[s][t] * fts[t][h]
        f32x4 acc2[4];
        #pragma unroll
        for (int hj = 0; hj < 4; ++hj)
            for (int r = 0; r < 4; ++r) acc2[hj][r] = 0.f;
        #pragma unroll
        for (int hj = 0; hj < 4; ++hj) {
            short8 f0 = *reinterpret_cast<const short8*>(&ftsT[16 * hj + m][8 * g]);
            short8 f1 = *reinterpret_cast<const short8*>(&ftsT[16 * hj + m][8 * g + 32]);
            acc2[hj] = __builtin_amdgcn_mfma_f32_16x16x32_bf16(adf0, f0, acc2[hj], 0, 0, 0);
            acc2[hj] = __builtin_amdgcn_mfma_f32_16x16x32_bf16(adf1, f1, acc2[hj], 0, 0, 0);
        }

        // 9. bias + PReLU + strip sums + h_mv row
        #pragma unroll
        for (int hj = 0; hj < 4; ++hj) {
            const int h = 16 * hj + m;
            float part = 0.f;
            #pragma unroll
            for (int r = 0; r < 4; ++r) {
                float v = acc2[hj][r] + bg[hj];
                v = (v >= 0.f) ? v : pa * v;
                const int s = s0i + r;
                if (s < SS - 1) part += v;
                else            out_hmv[(size_t)b * NH + h] = v;  // s == 63
            }
            part += __shfl_xor(part, 16);
            part += __shfl_xor(part, 32);
            if (g == 0) c_part[w][h] = part;
        }

        // 10. raw barrier #2
        asm volatile("s_waitcnt lgkmcnt(0)" ::: "memory");
        __builtin_amdgcn_s_barrier();
        asm volatile("" ::: "memory");

        // 11. c reduce + store
        if (tid < NH) {
            float tot = c_part[0][tid] + c_part[1][tid] + c_part[2][tid] + c_part[3][tid];
            out_c[(size_t)b * NH + tid] = tot * (1.0f / 63.0f);
        }
    }
}

// ---- kernel 2: bilinear logits via MFMA; one wave = 16 batches ----
__global__ __launch_bounds__(256) void bilinear_k(
    const float* __restrict__ hmv, const float* __restrict__ c,
    const unsigned short* __restrict__ wsB, const float* __restrict__ b_bil,
    float* __restrict__ logits)
{
    const int tid = threadIdx.x;
    const int w   = tid >> 6;
    const int l   = tid & 63;
    const int m   = l & 15;
    const int g   = l >> 4;
    const int bgrp = (blockIdx.x * 4 + w) * 16;    // 16 batches per wave

    // A frags: rows = batches (m), k = i
    const float4* hp = reinterpret_cast<const float4*>(hmv + (size_t)(bgrp + m) * NH);
    short8 af[2];
    af[0] = cvt8(hp[0 + 2 * g], hp[1 + 2 * g]);
    af[1] = cvt8(hp[8 + 2 * g], hp[9 + 2 * g]);

    const short8* wl = reinterpret_cast<const short8*>(wsB);
    f32x4 acc[4];
    #pragma unroll
    for (int nt = 0; nt < 4; ++nt)
        for (int r = 0; r < 4; ++r) acc[nt][r] = 0.f;
    #pragma unroll
    for (int kk = 0; kk < 2; ++kk) {
        #pragma unroll
        for (int nt = 0; nt < 4; ++nt) {
            short8 bf = wl[(kk * 4 + nt) * 64 + l];
            acc[nt] = __builtin_amdgcn_mfma_f32_16x16x32_bf16(af[kk], bf, acc[nt], 0, 0, 0);
        }
    }
    // lane holds v[b = bgrp+4g+r][j = 16nt+m]

    float t0[4] = {0.f, 0.f, 0.f, 0.f};
    float t1[4] = {0.f, 0.f, 0.f, 0.f};
    #pragma unroll
    for (int nt = 0; nt < 4; ++nt) {
        #pragma unroll
        for (int r = 0; r < 4; ++r) {
            const int bq = bgrp + 4 * g + r;
            const int bp = (bq == 0) ? (BB - 2) : (bq - 1);
            float cj = c[(size_t)bq * NH + 16 * nt + m];
            float cp = c[(size_t)bp * NH + 16 * nt + m];
            t0[r] = fmaf(acc[nt][r], cj, t0[r]);
            t1[r] = fmaf(acc[nt][r], cp, t1[r]);
        }
    }
    #pragma unroll
    for (int r = 0; r < 4; ++r) {
        #pragma unroll
        for (int off = 1; off < 16; off <<= 1) {
            t0[r] += __shfl_xor(t0[r], off);
            t1[r] += __shfl_xor(t1[r], off);
        }
    }
    if (m == 0) {
        const float bbv = b_bil[0];
        #pragma unroll
        for (int r = 0; r < 4; ++r) {
            const int bq = bgrp + 4 * g + r;
            logits[bq]      = t0[r] + bbv;
            logits[BB + bq] = t1[r] + bbv;
        }
    }
}

extern "C" void kernel_launch(void* const* d_in, const int* in_sizes, int n_in,
                              void* d_out, int out_size, void* d_ws, size_t ws_size,
                              hipStream_t stream) {
    const float* seq1    = (const float*)d_in[0];
    const float* adj     = (const float*)d_in[1];
    const float* W_fc    = (const float*)d_in[2];
    const float* b_gcn   = (const float*)d_in[3];
    const float* prelu_a = (const float*)d_in[4];
    const float* W_bil   = (const float*)d_in[5];
    const float* b_bil   = (const float*)d_in[6];

    float* out    = (float*)d_out;
    float* logits = out;                       // 2*BB
    float* hmv    = out + 2 * BB;              // BB*NH
    float* cc     = hmv + (size_t)BB * NH;     // BB*NH

    unsigned short* wsA = (unsigned short*)d_ws;        // 16 KiB W_fc frags
    unsigned short* wsB = wsA + NH * NIN;               //  8 KiB W_bil frags

    conv_w<<<(NH * NIN + NH * NH + 255) / 256, 256, 0, stream>>>(W_fc, W_bil, wsA, wsB);
    fused_gcn<<<GRID, 256, 0, stream>>>(seq1, adj, wsA, b_gcn, prelu_a, hmv, cc);
    bilinear_k<<<BB / 64, 256, 0, stream>>>(hmv, cc, wsB, b_bil, logits);
}